// Round 4
// baseline (95.442 us; speedup 1.0000x reference)
//
#include <hip/hip_runtime.h>
#include <math.h>

// Problem constants
#define Nn   8192
#define DXc  64
#define DZc  128
#define DYc  16
#define Hc   512
#define NKC  21     // k-chunks of 32 in concat K: 16 (S=512) + 4 (z=128) + 1 (y=16+pad)

typedef short bf16x8 __attribute__((ext_vector_type(8)));   // 8 bf16 = 4 VGPRs
typedef float f32x4  __attribute__((ext_vector_type(4)));

__device__ __forceinline__ float fast_tanh(float x) {
    float e = __expf(2.0f * x);             // exact limits at +/-inf, ~1e-7 rel err
    return 1.0f - 2.0f / (e + 1.0f);
}
__device__ __forceinline__ short f2bf(float f) {            // fp32 -> bf16 RNE
    unsigned u = __float_as_uint(f);
    return (short)((u + 0x7FFFu + ((u >> 16) & 1u)) >> 16);
}
__device__ __forceinline__ bf16x8 pack8(float4 a, float4 b) {
    bf16x8 r;
    r[0]=f2bf(a.x); r[1]=f2bf(a.y); r[2]=f2bf(a.z); r[3]=f2bf(a.w);
    r[4]=f2bf(b.x); r[5]=f2bf(b.y); r[6]=f2bf(b.z); r[7]=f2bf(b.w);
    return r;
}

// ===================== prep: weights -> MFMA-fragment-major bf16 =====================
// Fragment block = 1 KB: 64 lanes x 16 B.  Element (row r in 16-tile, k) of block:
//   off = (block*64 + ((k>>3)&3)*16 + (r&15)) * 8 + (k&7)
// Wb blocks: (jt, kc2)   jt=j>>4 in [0,32), kc2=k>>5 in [0,2)   -> block = jt*2+kc2
// Wf blocks: (zt, kc)    zt=z>>4 in [0,8),  kc in [0,21)        -> block = zt*21+kc
__global__ void prep_kernel(const float* __restrict__ W1,
                            const float* __restrict__ W2,
                            const float* __restrict__ A,
                            const float* __restrict__ Bm,
                            short* __restrict__ Wb,
                            short* __restrict__ Wf) {
    __shared__ float tile[64 * 129];     // 33 KB transpose staging
    const int blk = blockIdx.x, t = threadIdx.x;

    if (blk < 8) {                       // ---- W1 (64k x 512j): j-slab [64*blk, +64) ----
        const int jb = blk * 64;
#pragma unroll
        for (int p = 0; p < 16; p++) {
            int lin = p * 256 + t;
            int k = lin >> 6, jj = lin & 63;
            tile[jj * 65 + k] = W1[(size_t)k * Hc + jb + jj];   // coalesced
        }
        __syncthreads();
#pragma unroll
        for (int p = 0; p < 2; p++) {
            int cid = p * 256 + t;                  // 512 chunks
            int lane = cid & 63, q = lane >> 4, n16 = lane & 15;
            int kc2 = (cid >> 6) & 1, jt4 = cid >> 7;   // 0..3
            int jl = jt4 * 16 + n16, k0 = kc2 * 32 + q * 8;
            bf16x8 v;
#pragma unroll
            for (int i = 0; i < 8; i++) v[i] = f2bf(tile[jl * 65 + k0 + i]);
            int block = ((blk * 4 + jt4) * 2 + kc2);
            *(bf16x8*)(Wb + (size_t)(block * 64 + lane) * 8) = v;
        }
    } else if (blk < 16) {               // ---- W2 (512k x 128z): k-slab [64*(blk-8), +64) ----
        const int kb = (blk - 8) * 64;
#pragma unroll
        for (int p = 0; p < 32; p++) {
            int lin = p * 256 + t;
            int kk = lin >> 7, z = lin & 127;
            tile[kk * 129 + z] = W2[(size_t)(kb + kk) * DZc + z];  // coalesced
        }
        __syncthreads();
#pragma unroll
        for (int p = 0; p < 4; p++) {
            int cid = p * 256 + t;                  // 1024 chunks
            int lane = cid & 63, q = lane >> 4, n16 = lane & 15;
            int rest = cid >> 6;                    // 0..15
            int kc2 = rest & 1, zt = rest >> 1;     // zt 0..7
            int z = zt * 16 + n16, k0l = kc2 * 32 + q * 8;
            bf16x8 v;
#pragma unroll
            for (int i = 0; i < 8; i++) v[i] = f2bf(tile[(k0l + i) * 129 + z]);
            int kc = (kb >> 5) + kc2;
            *(bf16x8*)(Wf + (size_t)((zt * NKC + kc) * 64 + lane) * 8) = v;
        }
    } else if (blk < 24) {               // ---- -A^T: kc 16..19 ----
        int cid = (blk - 16) * 256 + t;             // 0..2047
        int lane = cid & 63, q = lane >> 4, n16 = lane & 15;
        int rest = cid >> 6;                        // 0..31
        int kcl = rest & 3, zt = rest >> 2;
        int z = zt * 16 + n16, c0 = kcl * 32 + q * 8;
        float4 a0 = *(const float4*)(A + (size_t)z * DZc + c0);
        float4 a1 = *(const float4*)(A + (size_t)z * DZc + c0 + 4);
        bf16x8 v;
        v[0]=f2bf(-a0.x); v[1]=f2bf(-a0.y); v[2]=f2bf(-a0.z); v[3]=f2bf(-a0.w);
        v[4]=f2bf(-a1.x); v[5]=f2bf(-a1.y); v[6]=f2bf(-a1.z); v[7]=f2bf(-a1.w);
        *(bf16x8*)(Wf + (size_t)((zt * NKC + 16 + kcl) * 64 + lane) * 8) = v;
    } else {                             // ---- -B^T + zero pad: kc 20 ----
#pragma unroll
        for (int p = 0; p < 2; p++) {
            int cid = p * 256 + t;                  // 0..511
            int lane = cid & 63, q = lane >> 4, n16 = lane & 15;
            int zt = cid >> 6;                      // 0..7
            int z = zt * 16 + n16;
            bf16x8 v = (bf16x8){0,0,0,0,0,0,0,0};
            if (q < 2) {
                float4 b0 = *(const float4*)(Bm + (size_t)z * DYc + q * 8);
                float4 b1 = *(const float4*)(Bm + (size_t)z * DYc + q * 8 + 4);
                v[0]=f2bf(-b0.x); v[1]=f2bf(-b0.y); v[2]=f2bf(-b0.z); v[3]=f2bf(-b0.w);
                v[4]=f2bf(-b1.x); v[5]=f2bf(-b1.y); v[6]=f2bf(-b1.z); v[7]=f2bf(-b1.w);
            }
            *(bf16x8*)(Wf + (size_t)((zt * NKC + 20) * 64 + lane) * 8) = v;
        }
    }
}

#define MFMA16(a, b, c) __builtin_amdgcn_mfma_f32_16x16x32_bf16((a), (b), (c), 0, 0, 0)

// ===================== main: 16 samples/block, 512 threads (8 waves) =====================
// phase B: wave w -> j in [64w, 64w+64); phase C: wave w -> z-tile w (16 z cols), full K.
__global__ __launch_bounds__(512, 4)
void pde_main(const float* __restrict__ z_pred,
              const float* __restrict__ x_label,
              const float* __restrict__ y_label,
              const float* __restrict__ b1,
              const short* __restrict__ Wb,
              const short* __restrict__ Wf,
              float* __restrict__ out) {
    __shared__ __align__(16) short sS[16 * 512];  // 16 KB, fragment-major S tile
    __shared__ float red[8][16];

    const int tid  = threadIdx.x;
    const int w    = tid >> 6;
    const int lane = tid & 63;
    const int n16  = lane & 15;
    const int q    = lane >> 4;
    const int n0   = blockIdx.x * 16;

    // --- x / tanh(x) A-fragments: A[m=n16][k=q*8+i], k-chunks {0..31},{32..63} ---
    const float* xp = x_label + (size_t)(n0 + n16) * DXc + q * 8;
    float4 x0 = *(const float4*)xp,        x1 = *(const float4*)(xp + 4);
    float4 x2 = *(const float4*)(xp + 32), x3 = *(const float4*)(xp + 36);
    bf16x8 ax0 = pack8(x0, x1), ax1 = pack8(x2, x3);
    bf16x8 at0, at1;
    {
        float v[16] = {x0.x,x0.y,x0.z,x0.w, x1.x,x1.y,x1.z,x1.w,
                       x2.x,x2.y,x2.z,x2.w, x3.x,x3.y,x3.z,x3.w};
#pragma unroll
        for (int i = 0; i < 8; i++) { at0[i] = f2bf(fast_tanh(v[i])); at1[i] = f2bf(fast_tanh(v[8 + i])); }
    }

    // --- phase B: 4 j-tiles, fully-coalesced 1KB weight blocks ---
#pragma unroll
    for (int t = 0; t < 4; t++) {
        const int jt = 4 * w + t;
        const short* bp = Wb + (size_t)(jt * 2 * 64 + lane) * 8;
        bf16x8 bw0 = *(const bf16x8*)bp;
        bf16x8 bw1 = *(const bf16x8*)(bp + 512);       // next kc2 block
        f32x4 h = (f32x4){0.f,0.f,0.f,0.f};
        f32x4 u = (f32x4){0.f,0.f,0.f,0.f};
        h = MFMA16(ax0, bw0, h);  h = MFMA16(ax1, bw1, h);
        u = MFMA16(at0, bw0, u);  u = MFMA16(at1, bw1, u);
        const float bj = b1[jt * 16 + n16];            // C col = n16 -> j
        const int j = jt * 16 + n16;
        const int sbase = (j >> 5) * 512 + ((j >> 3) & 3) * 128 + (j & 7);
#pragma unroll
        for (int reg = 0; reg < 4; reg++) {            // C row = q*4+reg -> sample
            float tv = fast_tanh(h[reg] + bj);
            float s  = (1.f - tv * tv) * u[reg];
            sS[sbase + (q * 4 + reg) * 8] = f2bf(s);   // frag-major; ~2-way bank aliasing
        }
    }

    // --- corrections (pre-barrier, overlap other waves' phase B): z-tile w ---
    const short* wfb = Wf + (size_t)(w * NKC * 64 + lane) * 8;   // kc stride = 512 bf16
    f32x4 acc = (f32x4){0.f,0.f,0.f,0.f};
    {
        const float* zp = z_pred + (size_t)(n0 + n16) * DZc + q * 8;
#pragma unroll
        for (int kcl = 0; kcl < 4; kcl++) {
            float4 a0 = *(const float4*)(zp + kcl * 32);
            float4 a1 = *(const float4*)(zp + kcl * 32 + 4);
            bf16x8 az = pack8(a0, a1);
            bf16x8 bz = *(const bf16x8*)(wfb + (16 + kcl) * 512);
            acc = MFMA16(az, bz, acc);
        }
        bf16x8 ay = (bf16x8){0,0,0,0,0,0,0,0};
        if (q < 2) {
            const float* yp = y_label + (size_t)(n0 + n16) * DYc + q * 8;
            ay = pack8(*(const float4*)yp, *(const float4*)(yp + 4));
        }
        acc = MFMA16(ay, *(const bf16x8*)(wfb + 20 * 512), acc);
    }

    __syncthreads();

    // --- phase C: S @ Wc over K=512, conflict-free consecutive-16B LDS reads ---
#pragma unroll
    for (int kc = 0; kc < 16; kc++) {
        bf16x8 sa = *(const bf16x8*)(sS + kc * 512 + lane * 8);
        bf16x8 bk = *(const bf16x8*)(wfb + kc * 512);
        acc = MFMA16(sa, bk, acc);
    }

    // --- epilogue: per-sample sum of squares over this wave's 16 z, cross-wave reduce ---
#pragma unroll
    for (int reg = 0; reg < 4; reg++) {
        float sq = acc[reg] * acc[reg];
        sq += __shfl_xor(sq, 1);
        sq += __shfl_xor(sq, 2);
        sq += __shfl_xor(sq, 4);
        sq += __shfl_xor(sq, 8);
        if (n16 == 0) red[w][q * 4 + reg] = sq;
    }
    __syncthreads();

    if (tid < 16) {
        float tot = 0.f;
#pragma unroll
        for (int i = 0; i < 8; i++) tot += red[i][tid];
        float nrm = sqrtf(tot);
        nrm += __shfl_xor(nrm, 1);
        nrm += __shfl_xor(nrm, 2);
        nrm += __shfl_xor(nrm, 4);
        nrm += __shfl_xor(nrm, 8);
        if (tid == 0) atomicAdd(out, nrm * (1.0f / (float)Nn));
    }
}

extern "C" void kernel_launch(void* const* d_in, const int* in_sizes, int n_in,
                              void* d_out, int out_size, void* d_ws, size_t ws_size,
                              hipStream_t stream) {
    const float* z_pred  = (const float*)d_in[0];
    const float* x_label = (const float*)d_in[1];
    const float* y_label = (const float*)d_in[2];
    const float* W1      = (const float*)d_in[3];
    const float* b1      = (const float*)d_in[4];
    const float* W2      = (const float*)d_in[5];
    // d_in[6] = b2: cancels in the Jacobian-vector product
    const float* A       = (const float*)d_in[7];
    const float* Bm      = (const float*)d_in[8];

    short* Wb = (short*)d_ws;                    // 32x2 blocks  * 1KB = 64 KB
    short* Wf = Wb + 512 * DXc;                  // 8x21 blocks  * 1KB = 168 KB

    hipMemsetAsync(d_out, 0, sizeof(float), stream);
    prep_kernel<<<25, 256, 0, stream>>>(W1, W2, A, Bm, Wb, Wf);
    pde_main<<<Nn / 16, 512, 0, stream>>>(z_pred, x_label, y_label, b1, Wb, Wf, (float*)d_out);
}

// Round 5
// 93.772 us; speedup vs baseline: 1.0178x; 1.0178x over previous
//
#include <hip/hip_runtime.h>
#include <math.h>

// Problem constants
#define Nn   8192
#define DXc  64
#define DZc  128
#define DYc  16
#define Hc   512
#define NKC  21     // k-chunks of 32 in concat K: 16 (S=512) + 4 (z=128) + 1 (y=16+pad)

typedef short bf16x8 __attribute__((ext_vector_type(8)));   // 8 bf16 = 4 VGPRs
typedef float f32x4  __attribute__((ext_vector_type(4)));

__device__ __forceinline__ float fast_tanh(float x) {
    float e = __expf(2.0f * x);             // exact limits at +/-inf, ~1e-7 rel err
    return 1.0f - 2.0f / (e + 1.0f);
}
__device__ __forceinline__ short f2bf(float f) {            // fp32 -> bf16 RNE
    unsigned u = __float_as_uint(f);
    return (short)((u + 0x7FFFu + ((u >> 16) & 1u)) >> 16);
}
__device__ __forceinline__ bf16x8 pack8(float4 a, float4 b) {
    bf16x8 r;
    r[0]=f2bf(a.x); r[1]=f2bf(a.y); r[2]=f2bf(a.z); r[3]=f2bf(a.w);
    r[4]=f2bf(b.x); r[5]=f2bf(b.y); r[6]=f2bf(b.z); r[7]=f2bf(b.w);
    return r;
}

// ===================== prep: weights -> MFMA-fragment-major bf16 =====================
// Fragment block = 1 KB: 64 lanes x 16 B; element (row r, k): off = block*512 + lane(r,k)*8 + (k&7)
// Wb blocks: (jt, kc2)  jt = j>>4 in [0,32), kc2 = k>>5 in [0,2)
// Wf blocks: (zt, kc)   zt = z>>4 in [0,8),  kc in [0,21)
__global__ void prep_kernel(const float* __restrict__ W1,
                            const float* __restrict__ W2,
                            const float* __restrict__ A,
                            const float* __restrict__ Bm,
                            short* __restrict__ Wb,
                            short* __restrict__ Wf,
                            float* __restrict__ out) {
    __shared__ float tile[64 * 129];     // 33 KB transpose staging
    const int blk = blockIdx.x, t = threadIdx.x;

    if (blk < 8) {                       // ---- W1 (64k x 512j): j-slab [64*blk, +64) ----
        const int jb = blk * 64;
#pragma unroll
        for (int p = 0; p < 16; p++) {
            int lin = p * 256 + t;
            int k = lin >> 6, jj = lin & 63;
            tile[jj * 65 + k] = W1[(size_t)k * Hc + jb + jj];   // coalesced
        }
        __syncthreads();
#pragma unroll
        for (int p = 0; p < 2; p++) {
            int cid = p * 256 + t;
            int lane = cid & 63, q = lane >> 4, n16 = lane & 15;
            int kc2 = (cid >> 6) & 1, jt4 = cid >> 7;
            int jl = jt4 * 16 + n16, k0 = kc2 * 32 + q * 8;
            bf16x8 v;
#pragma unroll
            for (int i = 0; i < 8; i++) v[i] = f2bf(tile[jl * 65 + k0 + i]);
            int block = ((blk * 4 + jt4) * 2 + kc2);
            *(bf16x8*)(Wb + (size_t)(block * 64 + lane) * 8) = v;
        }
    } else if (blk < 16) {               // ---- W2 (512k x 128z): k-slab [64*(blk-8), +64) ----
        const int kb = (blk - 8) * 64;
#pragma unroll
        for (int p = 0; p < 32; p++) {
            int lin = p * 256 + t;
            int kk = lin >> 7, z = lin & 127;
            tile[kk * 129 + z] = W2[(size_t)(kb + kk) * DZc + z];  // coalesced
        }
        __syncthreads();
#pragma unroll
        for (int p = 0; p < 4; p++) {
            int cid = p * 256 + t;
            int lane = cid & 63, q = lane >> 4, n16 = lane & 15;
            int rest = cid >> 6;
            int kc2 = rest & 1, zt = rest >> 1;
            int z = zt * 16 + n16, k0l = kc2 * 32 + q * 8;
            bf16x8 v;
#pragma unroll
            for (int i = 0; i < 8; i++) v[i] = f2bf(tile[(k0l + i) * 129 + z]);
            int kc = (kb >> 5) + kc2;
            *(bf16x8*)(Wf + (size_t)((zt * NKC + kc) * 64 + lane) * 8) = v;
        }
    } else if (blk < 24) {               // ---- -A^T: kc 16..19 ----
        int cid = (blk - 16) * 256 + t;
        int lane = cid & 63, q = lane >> 4, n16 = lane & 15;
        int rest = cid >> 6;
        int kcl = rest & 3, zt = rest >> 2;
        int z = zt * 16 + n16, c0 = kcl * 32 + q * 8;
        float4 a0 = *(const float4*)(A + (size_t)z * DZc + c0);
        float4 a1 = *(const float4*)(A + (size_t)z * DZc + c0 + 4);
        bf16x8 v;
        v[0]=f2bf(-a0.x); v[1]=f2bf(-a0.y); v[2]=f2bf(-a0.z); v[3]=f2bf(-a0.w);
        v[4]=f2bf(-a1.x); v[5]=f2bf(-a1.y); v[6]=f2bf(-a1.z); v[7]=f2bf(-a1.w);
        *(bf16x8*)(Wf + (size_t)((zt * NKC + 16 + kcl) * 64 + lane) * 8) = v;
    } else {                             // ---- -B^T + zero pad: kc 20; also zero d_out ----
        if (t == 0) out[0] = 0.f;
#pragma unroll
        for (int p = 0; p < 2; p++) {
            int cid = p * 256 + t;
            int lane = cid & 63, q = lane >> 4, n16 = lane & 15;
            int zt = cid >> 6;
            int z = zt * 16 + n16;
            bf16x8 v = (bf16x8){0,0,0,0,0,0,0,0};
            if (q < 2) {
                float4 b0 = *(const float4*)(Bm + (size_t)z * DYc + q * 8);
                float4 b1 = *(const float4*)(Bm + (size_t)z * DYc + q * 8 + 4);
                v[0]=f2bf(-b0.x); v[1]=f2bf(-b0.y); v[2]=f2bf(-b0.z); v[3]=f2bf(-b0.w);
                v[4]=f2bf(-b1.x); v[5]=f2bf(-b1.y); v[6]=f2bf(-b1.z); v[7]=f2bf(-b1.w);
            }
            *(bf16x8*)(Wf + (size_t)((zt * NKC + 20) * 64 + lane) * 8) = v;
        }
    }
}

#define MFMA16(a, b, c) __builtin_amdgcn_mfma_f32_16x16x32_bf16((a), (b), (c), 0, 0, 0)

// ===================== main: 16 samples/block, 256 threads (4 waves) =====================
// phase B: wave w -> j-tiles [8w, 8w+8); phase C: wave w -> z-tiles {2w, 2w+1}, full K.
__global__ __launch_bounds__(256, 4)
void pde_main(const float* __restrict__ z_pred,
              const float* __restrict__ x_label,
              const float* __restrict__ y_label,
              const float* __restrict__ b1,
              const short* __restrict__ Wb,
              const short* __restrict__ Wf,
              float* __restrict__ out) {
    __shared__ __align__(16) short sS[16 * 512];  // 16 KB, fragment-major S tile
    __shared__ float red[4][16];

    const int tid  = threadIdx.x;
    const int w    = tid >> 6;
    const int lane = tid & 63;
    const int n16  = lane & 15;
    const int q    = lane >> 4;
    const int n0   = blockIdx.x * 16;

    // --- x / tanh(x) A-fragments: A[m=n16][k=q*8+i], k-chunks {0..31},{32..63} ---
    const float* xp = x_label + (size_t)(n0 + n16) * DXc + q * 8;
    float4 x0 = *(const float4*)xp,        x1 = *(const float4*)(xp + 4);
    float4 x2 = *(const float4*)(xp + 32), x3 = *(const float4*)(xp + 36);
    bf16x8 ax0 = pack8(x0, x1), ax1 = pack8(x2, x3);
    bf16x8 at0, at1;
    {
        float v[16] = {x0.x,x0.y,x0.z,x0.w, x1.x,x1.y,x1.z,x1.w,
                       x2.x,x2.y,x2.z,x2.w, x3.x,x3.y,x3.z,x3.w};
#pragma unroll
        for (int i = 0; i < 8; i++) { at0[i] = f2bf(fast_tanh(v[i])); at1[i] = f2bf(fast_tanh(v[8 + i])); }
    }

    // --- phase B: 8 j-tiles per wave, fully-coalesced 1KB weight blocks ---
#pragma unroll
    for (int t = 0; t < 8; t++) {
        const int jt = 8 * w + t;
        const short* bp = Wb + (size_t)(jt * 2 * 64 + lane) * 8;
        bf16x8 bw0 = *(const bf16x8*)bp;
        bf16x8 bw1 = *(const bf16x8*)(bp + 512);       // kc2=1 block
        f32x4 h = (f32x4){0.f,0.f,0.f,0.f};
        f32x4 u = (f32x4){0.f,0.f,0.f,0.f};
        h = MFMA16(ax0, bw0, h);  h = MFMA16(ax1, bw1, h);
        u = MFMA16(at0, bw0, u);  u = MFMA16(at1, bw1, u);
        const float bj = b1[jt * 16 + n16];            // C col = n16 -> j
        const int j = jt * 16 + n16;
        const int sbase = (j >> 5) * 512 + ((j >> 3) & 3) * 128 + (j & 7);
#pragma unroll
        for (int reg = 0; reg < 4; reg++) {            // C row = q*4+reg -> sample
            float tv = fast_tanh(h[reg] + bj);
            float s  = (1.f - tv * tv) * u[reg];
            sS[sbase + (q * 4 + reg) * 8] = f2bf(s);   // fragment-major store
        }
    }

    // --- corrections (pre-barrier; overlap other waves' phase B): z-tiles 2w, 2w+1 ---
    const short* wf0 = Wf + (size_t)((2 * w)     * NKC * 64 + lane) * 8;  // kc stride = 512
    const short* wf1 = Wf + (size_t)((2 * w + 1) * NKC * 64 + lane) * 8;
    f32x4 acc0 = (f32x4){0.f,0.f,0.f,0.f};
    f32x4 acc1 = (f32x4){0.f,0.f,0.f,0.f};
    {
        const float* zp = z_pred + (size_t)(n0 + n16) * DZc + q * 8;
#pragma unroll
        for (int kcl = 0; kcl < 4; kcl++) {
            float4 a0 = *(const float4*)(zp + kcl * 32);
            float4 a1 = *(const float4*)(zp + kcl * 32 + 4);
            bf16x8 az = pack8(a0, a1);
            acc0 = MFMA16(az, *(const bf16x8*)(wf0 + (16 + kcl) * 512), acc0);
            acc1 = MFMA16(az, *(const bf16x8*)(wf1 + (16 + kcl) * 512), acc1);
        }
        bf16x8 ay = (bf16x8){0,0,0,0,0,0,0,0};
        if (q < 2) {
            const float* yp = y_label + (size_t)(n0 + n16) * DYc + q * 8;
            ay = pack8(*(const float4*)yp, *(const float4*)(yp + 4));
        }
        acc0 = MFMA16(ay, *(const bf16x8*)(wf0 + 20 * 512), acc0);
        acc1 = MFMA16(ay, *(const bf16x8*)(wf1 + 20 * 512), acc1);
    }

    // --- prefetch first 4 phase-C weight chunks per z-tile above the barrier ---
    bf16x8 pf0[4], pf1[4];
#pragma unroll
    for (int c = 0; c < 4; c++) {
        pf0[c] = *(const bf16x8*)(wf0 + c * 512);
        pf1[c] = *(const bf16x8*)(wf1 + c * 512);
    }

    __syncthreads();

    // --- phase C: S @ Wc over K=512; conflict-free consecutive-16B LDS reads ---
#pragma unroll
    for (int kc = 0; kc < 16; kc++) {
        bf16x8 sa = *(const bf16x8*)(sS + kc * 512 + lane * 8);
        bf16x8 b0 = (kc < 4) ? pf0[kc & 3] : *(const bf16x8*)(wf0 + kc * 512);
        bf16x8 b1f = (kc < 4) ? pf1[kc & 3] : *(const bf16x8*)(wf1 + kc * 512);
        acc0 = MFMA16(sa, b0, acc0);
        acc1 = MFMA16(sa, b1f, acc1);
    }

    // --- epilogue: per-sample sum of squares over this wave's 32 z, cross-wave reduce ---
#pragma unroll
    for (int reg = 0; reg < 4; reg++) {
        float sq = fmaf(acc0[reg], acc0[reg], acc1[reg] * acc1[reg]);
        sq += __shfl_xor(sq, 1);
        sq += __shfl_xor(sq, 2);
        sq += __shfl_xor(sq, 4);
        sq += __shfl_xor(sq, 8);
        if (n16 == 0) red[w][q * 4 + reg] = sq;
    }
    __syncthreads();

    if (tid < 16) {
        float tot = red[0][tid] + red[1][tid] + red[2][tid] + red[3][tid];
        float nrm = sqrtf(tot);
        nrm += __shfl_xor(nrm, 1);
        nrm += __shfl_xor(nrm, 2);
        nrm += __shfl_xor(nrm, 4);
        nrm += __shfl_xor(nrm, 8);
        if (tid == 0) atomicAdd(out, nrm * (1.0f / (float)Nn));
    }
}

extern "C" void kernel_launch(void* const* d_in, const int* in_sizes, int n_in,
                              void* d_out, int out_size, void* d_ws, size_t ws_size,
                              hipStream_t stream) {
    const float* z_pred  = (const float*)d_in[0];
    const float* x_label = (const float*)d_in[1];
    const float* y_label = (const float*)d_in[2];
    const float* W1      = (const float*)d_in[3];
    const float* b1      = (const float*)d_in[4];
    const float* W2      = (const float*)d_in[5];
    // d_in[6] = b2: cancels in the Jacobian-vector product
    const float* A       = (const float*)d_in[7];
    const float* Bm      = (const float*)d_in[8];

    short* Wb = (short*)d_ws;                    // 64 KB fragment-major W1
    short* Wf = Wb + 512 * DXc;                  // 168 KB fragment-major [W2; -A^T; -B^T]

    prep_kernel<<<25, 256, 0, stream>>>(W1, W2, A, Bm, Wb, Wf, (float*)d_out);
    pde_main<<<Nn / 16, 256, 0, stream>>>(z_pred, x_label, y_label, b1, Wb, Wf, (float*)d_out);
}

// Round 6
// 86.754 us; speedup vs baseline: 1.1001x; 1.0809x over previous
//
#include <hip/hip_runtime.h>
#include <math.h>

// Problem constants
#define Nn   8192
#define DXc  64
#define DZc  128
#define DYc  16
#define Hc   512
#define NKC  21     // k-chunks of 32 in concat K: 16 (S=512) + 4 (z=128) + 1 (y=16+pad)

typedef short bf16x8 __attribute__((ext_vector_type(8)));   // 8 bf16 = 4 VGPRs
typedef float f32x4  __attribute__((ext_vector_type(4)));

__device__ __forceinline__ float fast_tanh(float x) {
    float e = __expf(2.0f * x);             // exact limits at +/-inf, ~1e-7 rel err
    return 1.0f - 2.0f / (e + 1.0f);
}
__device__ __forceinline__ short f2bf(float f) {            // fp32 -> bf16 RNE
    unsigned u = __float_as_uint(f);
    return (short)((u + 0x7FFFu + ((u >> 16) & 1u)) >> 16);
}
__device__ __forceinline__ bf16x8 pack8(float4 a, float4 b) {
    bf16x8 r;
    r[0]=f2bf(a.x); r[1]=f2bf(a.y); r[2]=f2bf(a.z); r[3]=f2bf(a.w);
    r[4]=f2bf(b.x); r[5]=f2bf(b.y); r[6]=f2bf(b.z); r[7]=f2bf(b.w);
    return r;
}

// ===================== prep: flat, one bf16x8 chunk per thread =====================
// Fragment block = 1 KB: 64 lanes x 16 B.
// Wb chunk c in [0,4096): block=c>>6 (= jt*2+kc2), lane=c&63 (= q*16 + (j&15)),
//                         element i = W1T[j = (block>>1)*16+(lane&15)][k = (block&1)*32+(lane>>4)*8+i]
// Wf chunk c2 in [0,10752): block=c2>>6 (= zt*21+kc), lane: z=(block/21)*16+(lane&15),
//                           k = (block%21)*32+(lane>>4)*8+i  over concat K=[W2 | -A^T | -B^T | 0]
__global__ __launch_bounds__(256)
void prep_kernel(const float* __restrict__ W1,
                 const float* __restrict__ W2,
                 const float* __restrict__ A,
                 const float* __restrict__ Bm,
                 short* __restrict__ Wb,
                 short* __restrict__ Wf,
                 float* __restrict__ out) {
    int c = blockIdx.x * 256 + threadIdx.x;
    if (c == 0) out[0] = 0.f;

    if (c < 4096) {                       // ---- W1 -> Wb ----
        int lane = c & 63, block = c >> 6;
        int n16 = lane & 15, q = lane >> 4;
        int j = (block >> 1) * 16 + n16;
        int k0 = (block & 1) * 32 + q * 8;
        bf16x8 v;
#pragma unroll
        for (int i = 0; i < 8; i++) v[i] = f2bf(W1[(size_t)(k0 + i) * Hc + j]);
        *(bf16x8*)(Wb + (size_t)c * 8) = v;
    } else {                              // ---- [W2; -A^T; -B^T; 0] -> Wf ----
        int c2 = c - 4096;                // < 10752
        int lane = c2 & 63, block = c2 >> 6;          // block < 168
        int zt = block / 21, kc = block % 21;
        int n16 = lane & 15, q = lane >> 4;
        int z = zt * 16 + n16;
        bf16x8 v = (bf16x8){0,0,0,0,0,0,0,0};
        if (kc < 16) {
            int k0 = kc * 32 + q * 8;
#pragma unroll
            for (int i = 0; i < 8; i++) v[i] = f2bf(W2[(size_t)(k0 + i) * DZc + z]);
        } else if (kc < 20) {
            int c0 = (kc - 16) * 32 + q * 8;
            float4 a0 = *(const float4*)(A + (size_t)z * DZc + c0);
            float4 a1 = *(const float4*)(A + (size_t)z * DZc + c0 + 4);
            v[0]=f2bf(-a0.x); v[1]=f2bf(-a0.y); v[2]=f2bf(-a0.z); v[3]=f2bf(-a0.w);
            v[4]=f2bf(-a1.x); v[5]=f2bf(-a1.y); v[6]=f2bf(-a1.z); v[7]=f2bf(-a1.w);
        } else if (q < 2) {
            float4 b0 = *(const float4*)(Bm + (size_t)z * DYc + q * 8);
            float4 b1 = *(const float4*)(Bm + (size_t)z * DYc + q * 8 + 4);
            v[0]=f2bf(-b0.x); v[1]=f2bf(-b0.y); v[2]=f2bf(-b0.z); v[3]=f2bf(-b0.w);
            v[4]=f2bf(-b1.x); v[5]=f2bf(-b1.y); v[6]=f2bf(-b1.z); v[7]=f2bf(-b1.w);
        }
        *(bf16x8*)(Wf + (size_t)c2 * 8) = v;
    }
}

#define MFMA16(a, b, c) __builtin_amdgcn_mfma_f32_16x16x32_bf16((a), (b), (c), 0, 0, 0)

// ===================== main: 16 samples/block, 256 threads (4 waves) =====================
// phase B: wave w -> j-tiles [8w, 8w+8); phase C: wave w -> z-tiles {2w, 2w+1}, full K.
__global__ __launch_bounds__(256, 4)
void pde_main(const float* __restrict__ z_pred,
              const float* __restrict__ x_label,
              const float* __restrict__ y_label,
              const float* __restrict__ b1,
              const short* __restrict__ Wb,
              const short* __restrict__ Wf,
              float* __restrict__ out) {
    __shared__ __align__(16) short sS[16 * 512];  // 16 KB, fragment-major S tile
    __shared__ float red[4][16];

    const int tid  = threadIdx.x;
    const int w    = tid >> 6;
    const int lane = tid & 63;
    const int n16  = lane & 15;
    const int q    = lane >> 4;
    const int n0   = blockIdx.x * 16;

    // --- x / tanh(x) A-fragments: A[m=n16][k=q*8+i], k-chunks {0..31},{32..63} ---
    const float* xp = x_label + (size_t)(n0 + n16) * DXc + q * 8;
    float4 x0 = *(const float4*)xp,        x1 = *(const float4*)(xp + 4);
    float4 x2 = *(const float4*)(xp + 32), x3 = *(const float4*)(xp + 36);
    bf16x8 ax0 = pack8(x0, x1), ax1 = pack8(x2, x3);
    bf16x8 at0, at1;
    {
        float v[16] = {x0.x,x0.y,x0.z,x0.w, x1.x,x1.y,x1.z,x1.w,
                       x2.x,x2.y,x2.z,x2.w, x3.x,x3.y,x3.z,x3.w};
#pragma unroll
        for (int i = 0; i < 8; i++) { at0[i] = f2bf(fast_tanh(v[i])); at1[i] = f2bf(fast_tanh(v[8 + i])); }
    }

    // --- phase B: 8 j-tiles per wave, fully-coalesced 1KB weight blocks ---
#pragma unroll
    for (int t = 0; t < 8; t++) {
        const int jt = 8 * w + t;
        const short* bp = Wb + (size_t)(jt * 2 * 64 + lane) * 8;
        bf16x8 bw0 = *(const bf16x8*)bp;
        bf16x8 bw1 = *(const bf16x8*)(bp + 512);       // kc2=1 block
        f32x4 h = (f32x4){0.f,0.f,0.f,0.f};
        f32x4 u = (f32x4){0.f,0.f,0.f,0.f};
        h = MFMA16(ax0, bw0, h);  h = MFMA16(ax1, bw1, h);
        u = MFMA16(at0, bw0, u);  u = MFMA16(at1, bw1, u);
        const float bj = b1[jt * 16 + n16];            // C col = n16 -> j
        const int j = jt * 16 + n16;
        const int sbase = (j >> 5) * 512 + ((j >> 3) & 3) * 128 + (j & 7);
#pragma unroll
        for (int reg = 0; reg < 4; reg++) {            // C row = q*4+reg -> sample
            float tv = fast_tanh(h[reg] + bj);
            float s  = (1.f - tv * tv) * u[reg];
            sS[sbase + (q * 4 + reg) * 8] = f2bf(s);   // fragment-major store
        }
    }

    // --- corrections (pre-barrier; overlap other waves' phase B): z-tiles 2w, 2w+1 ---
    const short* wf0 = Wf + (size_t)((2 * w)     * NKC * 64 + lane) * 8;  // kc stride = 512
    const short* wf1 = Wf + (size_t)((2 * w + 1) * NKC * 64 + lane) * 8;
    f32x4 acc0 = (f32x4){0.f,0.f,0.f,0.f};
    f32x4 acc1 = (f32x4){0.f,0.f,0.f,0.f};
    {
        const float* zp = z_pred + (size_t)(n0 + n16) * DZc + q * 8;
#pragma unroll
        for (int kcl = 0; kcl < 4; kcl++) {
            float4 a0 = *(const float4*)(zp + kcl * 32);
            float4 a1 = *(const float4*)(zp + kcl * 32 + 4);
            bf16x8 az = pack8(a0, a1);
            acc0 = MFMA16(az, *(const bf16x8*)(wf0 + (16 + kcl) * 512), acc0);
            acc1 = MFMA16(az, *(const bf16x8*)(wf1 + (16 + kcl) * 512), acc1);
        }
        bf16x8 ay = (bf16x8){0,0,0,0,0,0,0,0};
        if (q < 2) {
            const float* yp = y_label + (size_t)(n0 + n16) * DYc + q * 8;
            ay = pack8(*(const float4*)yp, *(const float4*)(yp + 4));
        }
        acc0 = MFMA16(ay, *(const bf16x8*)(wf0 + 20 * 512), acc0);
        acc1 = MFMA16(ay, *(const bf16x8*)(wf1 + 20 * 512), acc1);
    }

    __syncthreads();

    // --- phase C: S @ Wc over K=512; conflict-free consecutive-16B LDS reads ---
#pragma unroll
    for (int kc = 0; kc < 16; kc++) {
        bf16x8 sa = *(const bf16x8*)(sS + kc * 512 + lane * 8);
        acc0 = MFMA16(sa, *(const bf16x8*)(wf0 + kc * 512), acc0);
        acc1 = MFMA16(sa, *(const bf16x8*)(wf1 + kc * 512), acc1);
    }

    // --- epilogue: per-sample sum of squares over this wave's 32 z, cross-wave reduce ---
#pragma unroll
    for (int reg = 0; reg < 4; reg++) {
        float sq = fmaf(acc0[reg], acc0[reg], acc1[reg] * acc1[reg]);
        sq += __shfl_xor(sq, 1);
        sq += __shfl_xor(sq, 2);
        sq += __shfl_xor(sq, 4);
        sq += __shfl_xor(sq, 8);
        if (n16 == 0) red[w][q * 4 + reg] = sq;
    }
    __syncthreads();

    if (tid < 16) {
        float tot = red[0][tid] + red[1][tid] + red[2][tid] + red[3][tid];
        float nrm = sqrtf(tot);
        nrm += __shfl_xor(nrm, 1);
        nrm += __shfl_xor(nrm, 2);
        nrm += __shfl_xor(nrm, 4);
        nrm += __shfl_xor(nrm, 8);
        if (tid == 0) atomicAdd(out, nrm * (1.0f / (float)Nn));
    }
}

extern "C" void kernel_launch(void* const* d_in, const int* in_sizes, int n_in,
                              void* d_out, int out_size, void* d_ws, size_t ws_size,
                              hipStream_t stream) {
    const float* z_pred  = (const float*)d_in[0];
    const float* x_label = (const float*)d_in[1];
    const float* y_label = (const float*)d_in[2];
    const float* W1      = (const float*)d_in[3];
    const float* b1      = (const float*)d_in[4];
    const float* W2      = (const float*)d_in[5];
    // d_in[6] = b2: cancels in the Jacobian-vector product
    const float* A       = (const float*)d_in[7];
    const float* Bm      = (const float*)d_in[8];

    short* Wb = (short*)d_ws;                    // 64 KB fragment-major W1
    short* Wf = Wb + 512 * DXc;                  // 168 KB fragment-major [W2; -A^T; -B^T]

    prep_kernel<<<58, 256, 0, stream>>>(W1, W2, A, Bm, Wb, Wf, (float*)d_out);
    pde_main<<<Nn / 16, 256, 0, stream>>>(z_pred, x_label, y_label, b1, Wb, Wf, (float*)d_out);
}

// Round 7
// 86.280 us; speedup vs baseline: 1.1062x; 1.0055x over previous
//
#include <hip/hip_runtime.h>
#include <math.h>

// Problem constants
#define Nn   8192
#define DXc  64
#define DZc  128
#define DYc  16
#define Hc   512
#define NKC  21     // k-chunks of 32 in concat K: 16 (S=512) + 4 (z=128) + 1 (y=16+pad)

typedef short bf16x8 __attribute__((ext_vector_type(8)));   // 8 bf16 = 4 VGPRs
typedef float f32x4  __attribute__((ext_vector_type(4)));

__device__ __forceinline__ float fast_tanh(float x) {
    float e = __expf(2.0f * x);             // exact limits at +/-inf, ~1e-7 rel err
    return 1.0f - 2.0f / (e + 1.0f);
}
__device__ __forceinline__ short f2bf(float f) {            // fp32 -> bf16 RNE
    unsigned u = __float_as_uint(f);
    return (short)((u + 0x7FFFu + ((u >> 16) & 1u)) >> 16);
}
__device__ __forceinline__ bf16x8 pack8(float4 a, float4 b) {
    bf16x8 r;
    r[0]=f2bf(a.x); r[1]=f2bf(a.y); r[2]=f2bf(a.z); r[3]=f2bf(a.w);
    r[4]=f2bf(b.x); r[5]=f2bf(b.y); r[6]=f2bf(b.z); r[7]=f2bf(b.w);
    return r;
}

// ===================== prep: flat, one bf16x8 chunk per thread (58 blocks) =====================
// Fragment block = 1 KB: 64 lanes x 16 B.
// Wb chunk c in [0,4096): block=c>>6 (= jt*2+kc2); element i = W1[k][j],
//   j=(block>>1)*16+(lane&15), k=(block&1)*32+(lane>>4)*8+i
// Wf chunk c2 in [0,10752): block = zt*21+kc; z=(block/21)*16+(lane&15),
//   k=(block%21)*32+(lane>>4)*8+i over concat K=[W2 | -A^T | -B^T | 0]
__global__ __launch_bounds__(256)
void prep_kernel(const float* __restrict__ W1,
                 const float* __restrict__ W2,
                 const float* __restrict__ A,
                 const float* __restrict__ Bm,
                 short* __restrict__ Wb,
                 short* __restrict__ Wf,
                 float* __restrict__ out) {
    int c = blockIdx.x * 256 + threadIdx.x;
    if (c == 0) out[0] = 0.f;

    if (c < 4096) {                       // ---- W1 -> Wb ----
        int lane = c & 63, block = c >> 6;
        int n16 = lane & 15, q = lane >> 4;
        int j = (block >> 1) * 16 + n16;
        int k0 = (block & 1) * 32 + q * 8;
        bf16x8 v;
#pragma unroll
        for (int i = 0; i < 8; i++) v[i] = f2bf(W1[(size_t)(k0 + i) * Hc + j]);
        *(bf16x8*)(Wb + (size_t)c * 8) = v;
    } else {                              // ---- [W2; -A^T; -B^T; 0] -> Wf ----
        int c2 = c - 4096;                // < 10752
        int lane = c2 & 63, block = c2 >> 6;          // block < 168
        int zt = block / 21, kc = block % 21;
        int n16 = lane & 15, q = lane >> 4;
        int z = zt * 16 + n16;
        bf16x8 v = (bf16x8){0,0,0,0,0,0,0,0};
        if (kc < 16) {
            int k0 = kc * 32 + q * 8;
#pragma unroll
            for (int i = 0; i < 8; i++) v[i] = f2bf(W2[(size_t)(k0 + i) * DZc + z]);
        } else if (kc < 20) {
            int c0 = (kc - 16) * 32 + q * 8;
            float4 a0 = *(const float4*)(A + (size_t)z * DZc + c0);
            float4 a1 = *(const float4*)(A + (size_t)z * DZc + c0 + 4);
            v[0]=f2bf(-a0.x); v[1]=f2bf(-a0.y); v[2]=f2bf(-a0.z); v[3]=f2bf(-a0.w);
            v[4]=f2bf(-a1.x); v[5]=f2bf(-a1.y); v[6]=f2bf(-a1.z); v[7]=f2bf(-a1.w);
        } else if (q < 2) {
            float4 b0 = *(const float4*)(Bm + (size_t)z * DYc + q * 8);
            float4 b1 = *(const float4*)(Bm + (size_t)z * DYc + q * 8 + 4);
            v[0]=f2bf(-b0.x); v[1]=f2bf(-b0.y); v[2]=f2bf(-b0.z); v[3]=f2bf(-b0.w);
            v[4]=f2bf(-b1.x); v[5]=f2bf(-b1.y); v[6]=f2bf(-b1.z); v[7]=f2bf(-b1.w);
        }
        *(bf16x8*)(Wf + (size_t)c2 * 8) = v;
    }
}

#define MFMA16(a, b, c) __builtin_amdgcn_mfma_f32_16x16x32_bf16((a), (b), (c), 0, 0, 0)

// ===================== main: 32 samples/block, 512 threads (8 waves), 256 blocks =====================
// Weight fragments loaded ONCE per wave and reused for both 16-sample groups.
// phase B: wave w -> j-tiles [4w, 4w+4) x 2 groups; phase C: wave w -> z-tile w, full K, 2 groups.
__global__ __launch_bounds__(512, 2)
void pde_main(const float* __restrict__ z_pred,
              const float* __restrict__ x_label,
              const float* __restrict__ y_label,
              const float* __restrict__ b1,
              const short* __restrict__ Wb,
              const short* __restrict__ Wf,
              float* __restrict__ out) {
    __shared__ __align__(16) short sS[2][16 * 512];  // 32 KB, fragment-major S tiles (2 groups)
    __shared__ float red[8][2][16];

    const int tid  = threadIdx.x;
    const int w    = tid >> 6;
    const int lane = tid & 63;
    const int n16  = lane & 15;
    const int q    = lane >> 4;
    const int n0   = blockIdx.x * 32;

    // --- x / tanh(x) A-fragments for both sample groups ---
    bf16x8 ax0[2], ax1[2], at0[2], at1[2];
#pragma unroll
    for (int g = 0; g < 2; g++) {
        const float* xp = x_label + (size_t)(n0 + g * 16 + n16) * DXc + q * 8;
        float4 x0 = *(const float4*)xp,        x1 = *(const float4*)(xp + 4);
        float4 x2 = *(const float4*)(xp + 32), x3 = *(const float4*)(xp + 36);
        ax0[g] = pack8(x0, x1);  ax1[g] = pack8(x2, x3);
        float v[16] = {x0.x,x0.y,x0.z,x0.w, x1.x,x1.y,x1.z,x1.w,
                       x2.x,x2.y,x2.z,x2.w, x3.x,x3.y,x3.z,x3.w};
#pragma unroll
        for (int i = 0; i < 8; i++) { at0[g][i] = f2bf(fast_tanh(v[i])); at1[g][i] = f2bf(fast_tanh(v[8 + i])); }
    }

    // --- phase B: 4 j-tiles per wave, weight frags reused across groups ---
#pragma unroll
    for (int t = 0; t < 4; t++) {
        const int jt = 4 * w + t;
        const short* bp = Wb + (size_t)(jt * 2 * 64 + lane) * 8;
        bf16x8 bw0 = *(const bf16x8*)bp;
        bf16x8 bw1 = *(const bf16x8*)(bp + 512);       // kc2=1 block
        const float bj = b1[jt * 16 + n16];            // C col = n16 -> j (same both groups)
        const int j = jt * 16 + n16;
        const int sbase = (j >> 5) * 512 + ((j >> 3) & 3) * 128 + (j & 7);
#pragma unroll
        for (int g = 0; g < 2; g++) {
            f32x4 h = (f32x4){0.f,0.f,0.f,0.f};
            f32x4 u = (f32x4){0.f,0.f,0.f,0.f};
            h = MFMA16(ax0[g], bw0, h);  h = MFMA16(ax1[g], bw1, h);
            u = MFMA16(at0[g], bw0, u);  u = MFMA16(at1[g], bw1, u);
#pragma unroll
            for (int reg = 0; reg < 4; reg++) {        // C row = q*4+reg -> sample
                float tv = fast_tanh(h[reg] + bj);
                float s  = (1.f - tv * tv) * u[reg];
                sS[g][sbase + (q * 4 + reg) * 8] = f2bf(s);
            }
        }
    }

    // --- corrections (pre-barrier; overlap other waves' phase B): z-tile w ---
    const short* wfb = Wf + (size_t)(w * NKC * 64 + lane) * 8;   // kc stride = 512 bf16
    f32x4 acc[2] = {(f32x4){0.f,0.f,0.f,0.f}, (f32x4){0.f,0.f,0.f,0.f}};
    {
#pragma unroll
        for (int kcl = 0; kcl < 4; kcl++) {
            bf16x8 bz = *(const bf16x8*)(wfb + (16 + kcl) * 512);
#pragma unroll
            for (int g = 0; g < 2; g++) {
                const float* zp = z_pred + (size_t)(n0 + g * 16 + n16) * DZc + kcl * 32 + q * 8;
                bf16x8 az = pack8(*(const float4*)zp, *(const float4*)(zp + 4));
                acc[g] = MFMA16(az, bz, acc[g]);
            }
        }
        bf16x8 by = *(const bf16x8*)(wfb + 20 * 512);
#pragma unroll
        for (int g = 0; g < 2; g++) {
            bf16x8 ay = (bf16x8){0,0,0,0,0,0,0,0};
            if (q < 2) {
                const float* yp = y_label + (size_t)(n0 + g * 16 + n16) * DYc + q * 8;
                ay = pack8(*(const float4*)yp, *(const float4*)(yp + 4));
            }
            acc[g] = MFMA16(ay, by, acc[g]);
        }
    }

    __syncthreads();

    // --- phase C: S @ Wc over K=512; weight frag loaded once, used for both groups ---
#pragma unroll
    for (int kc = 0; kc < 16; kc++) {
        bf16x8 bk = *(const bf16x8*)(wfb + kc * 512);
        bf16x8 sa0 = *(const bf16x8*)(sS[0] + kc * 512 + lane * 8);
        bf16x8 sa1 = *(const bf16x8*)(sS[1] + kc * 512 + lane * 8);
        acc[0] = MFMA16(sa0, bk, acc[0]);
        acc[1] = MFMA16(sa1, bk, acc[1]);
    }

    // --- epilogue: per-sample sum of squares over this wave's 16 z, cross-wave reduce ---
#pragma unroll
    for (int g = 0; g < 2; g++) {
#pragma unroll
        for (int reg = 0; reg < 4; reg++) {
            float sq = acc[g][reg] * acc[g][reg];
            sq += __shfl_xor(sq, 1);
            sq += __shfl_xor(sq, 2);
            sq += __shfl_xor(sq, 4);
            sq += __shfl_xor(sq, 8);
            if (n16 == 0) red[w][g][q * 4 + reg] = sq;
        }
    }
    __syncthreads();

    if (tid < 32) {
        const int g = tid >> 4, r = tid & 15;
        float tot = 0.f;
#pragma unroll
        for (int i = 0; i < 8; i++) tot += red[i][g][r];
        float nrm = sqrtf(tot);
        nrm += __shfl_xor(nrm, 1);
        nrm += __shfl_xor(nrm, 2);
        nrm += __shfl_xor(nrm, 4);
        nrm += __shfl_xor(nrm, 8);
        nrm += __shfl_xor(nrm, 16);
        if (tid == 0) atomicAdd(out, nrm * (1.0f / (float)Nn));
    }
}

extern "C" void kernel_launch(void* const* d_in, const int* in_sizes, int n_in,
                              void* d_out, int out_size, void* d_ws, size_t ws_size,
                              hipStream_t stream) {
    const float* z_pred  = (const float*)d_in[0];
    const float* x_label = (const float*)d_in[1];
    const float* y_label = (const float*)d_in[2];
    const float* W1      = (const float*)d_in[3];
    const float* b1      = (const float*)d_in[4];
    const float* W2      = (const float*)d_in[5];
    // d_in[6] = b2: cancels in the Jacobian-vector product
    const float* A       = (const float*)d_in[7];
    const float* Bm      = (const float*)d_in[8];

    short* Wb = (short*)d_ws;                    // 64 KB fragment-major W1
    short* Wf = Wb + 512 * DXc;                  // 168 KB fragment-major [W2; -A^T; -B^T]

    prep_kernel<<<58, 256, 0, stream>>>(W1, W2, A, Bm, Wb, Wf, (float*)d_out);
    pde_main<<<Nn / 32, 512, 0, stream>>>(z_pred, x_label, y_label, b1, Wb, Wf, (float*)d_out);
}